// Round 5
// baseline (272.514 us; speedup 1.0000x reference)
//
#include <hip/hip_runtime.h>

#define HBITS 19u
#define HSIZE (1u << HBITS)
#define HMASK (HSIZE - 1u)
#define ECAP  (1 << 20)           // extras capacity (entries)
#define EMPTY64 0xFFFFFFFFFFFFFFFFull

constexpr int CD = 41, CH = 1024, CW = 1024;

// ---------------- setup: clear hash table, flags, counters ----------------

__global__ __launch_bounds__(256) void setup(unsigned long long* __restrict__ tab,
                                             int* __restrict__ flags, int n,
                                             int* __restrict__ cnt, int* __restrict__ scnt) {
    unsigned i = blockIdx.x * blockDim.x + threadIdx.x;
    if (i < HSIZE) tab[i] = EMPTY64;
    if (i < (unsigned)n) flags[i] = 0;
    if (i == 0) { *cnt = 0; *scnt = 0; }
}

// ---------------- hash: 64-bit records (idx<<32 | lin), linear probe ----------------

__global__ __launch_bounds__(256) void hash_insert(const int* __restrict__ coors, int n,
                                                   unsigned long long* __restrict__ tab) {
    int i = blockIdx.x * blockDim.x + threadIdx.x;
    if (i >= n) return;
    int b = coors[4 * i], z = coors[4 * i + 1], y = coors[4 * i + 2], x = coors[4 * i + 3];
    unsigned lin = (((unsigned)b * CD + (unsigned)z) * CH + (unsigned)y) * CW + (unsigned)x;
    unsigned h = (lin * 2654435761u) >> (32u - HBITS);
    unsigned long long rec = ((unsigned long long)(unsigned)i << 32) | (unsigned long long)lin;
    while (true) {
        unsigned long long prev = atomicCAS(&tab[h], EMPTY64, rec);
        if (prev == EMPTY64) break;
        h = (h + 1u) & HMASK;
    }
}

__device__ __forceinline__ int hash_lookup(unsigned lin, const unsigned long long* __restrict__ tab) {
    unsigned h = (lin * 2654435761u) >> (32u - HBITS);
    while (true) {
        unsigned long long v = tab[h];
        if ((unsigned)v == lin) return (int)(v >> 32);
        if (v == EMPTY64) return -1;
        h = (h + 1u) & HMASK;
    }
}

// ---------------- extras + S membership (mirror symmetry, scan k<13) ----------------

__global__ __launch_bounds__(256) void build_extras(const int* __restrict__ coors, int n,
                                                    const unsigned long long* __restrict__ tab,
                                                    int2* __restrict__ extras,
                                                    int* __restrict__ cnt,
                                                    int* __restrict__ flags) {
    int i = blockIdx.x * blockDim.x + threadIdx.x;
    if (i >= n) return;
    int b = coors[4 * i], z = coors[4 * i + 1], y = coors[4 * i + 2], x = coors[4 * i + 3];
    for (int k = 0; k < 13; ++k) {
        int dz = k / 9 - 1, dy = (k / 3) % 3 - 1, dx = k % 3 - 1;
        int nz = z + dz, ny = y + dy, nx = x + dx;
        if (nz < 0 || nz >= CD || ny < 0 || ny >= CH || nx < 0 || nx >= CW) continue;
        unsigned lin = (((unsigned)b * CD + (unsigned)nz) * CH + (unsigned)ny) * CW + (unsigned)nx;
        int j = hash_lookup(lin, tab);
        if (j >= 0) {
            int pos = atomicAdd(cnt, 2);
            if (pos + 1 < ECAP) {
                extras[pos]     = make_int2((i << 5) | k,        j);
                extras[pos + 1] = make_int2((j << 5) | (26 - k), i);
                flags[i] = 1;
                flags[j] = 1;
            }
        }
    }
}

__global__ __launch_bounds__(256) void compact_S(const int* __restrict__ flags, int n,
                                                 int* __restrict__ Slist, int* __restrict__ scnt) {
    int i = blockIdx.x * blockDim.x + threadIdx.x;
    if (i < n && flags[i]) { int s = atomicAdd(scnt, 1); Slist[s] = i; }
}

// ---------------- mm64: C = A @ B, 64x64 row-major ----------------

__global__ __launch_bounds__(256) void mm64(const float* __restrict__ A,
                                            const float* __restrict__ B,
                                            float* __restrict__ C) {
    int e = blockIdx.x * 256 + threadIdx.x;
    int r = e >> 6, c = e & 63;
    float s0 = 0.f, s1 = 0.f;
#pragma unroll
    for (int k = 0; k < 64; k += 2) {
        s0 = fmaf(A[r * 64 + k],     B[k * 64 + c],       s0);
        s1 = fmaf(A[r * 64 + k + 1], B[(k + 1) * 64 + c], s1);
    }
    C[e] = s0 + s1;
}

// ---------------- tiled row GEMM: out[p] = x[p] @ Wm (row-major [cin][cout]) --------
// 192 points/block (3 waves, 64 points/wave). X staged in LDS (coalesced float4 in,
// stride-65 pad -> compute reads are 2-way bank = free). lane = point; acc[64] static.
// W rows via uniform s_load (16KB, scalar-cache hot). Output bounced through LDS for
// coalesced float4 stores.

#define GSTRIDE 65

__global__ __launch_bounds__(192, 2) void gemm_tile(const float* __restrict__ xin,
                                                    float* __restrict__ xout,
                                                    const float* __restrict__ Wm,
                                                    const int* __restrict__ list,     // null -> identity
                                                    const int* __restrict__ listCnt,  // null -> n
                                                    int n) {
    __shared__ float Xs[192 * GSTRIDE];   // 49,920 B
    int t = threadIdx.x;
    int lane = t & 63;
    int wv = t >> 6;
    int cnt = listCnt ? *listCnt : n;
    if (cnt <= 0) return;
    int ntiles = (cnt + 191) / 192;

    for (int tile = blockIdx.x; tile < ntiles; tile += gridDim.x) {
        int base = tile * 192;
        __syncthreads();                               // Xs reuse guard
#pragma unroll
        for (int it = 0; it < 16; ++it) {              // global -> LDS, coalesced
            int f = it * 192 + t;                      // float4 id 0..3071
            int row = f >> 4, c4 = f & 15;
            int gr = base + row;
            int src = gr < cnt ? gr : cnt - 1;
            if (list) src = list[src];
            float4 v = *(const float4*)(xin + (size_t)src * 64 + c4 * 4);
            float* d = &Xs[row * GSTRIDE + c4 * 4];
            d[0] = v.x; d[1] = v.y; d[2] = v.z; d[3] = v.w;
        }
        __syncthreads();

        int myrow = wv * 64 + lane;
        float* xr = &Xs[myrow * GSTRIDE];
        float acc[64];
#pragma unroll
        for (int o = 0; o < 64; ++o) acc[o] = 0.f;
#pragma unroll 4
        for (int c = 0; c < 64; ++c) {
            float xc = xr[c];
            const float* wr = Wm + c * 64;             // uniform -> s_load
#pragma unroll
            for (int o = 0; o < 64; ++o) acc[o] = fmaf(xc, wr[o], acc[o]);
        }
        // each lane overwrites only its own row (only it read that row)
#pragma unroll
        for (int o = 0; o < 64; ++o) xr[o] = acc[o];
        __syncthreads();
#pragma unroll
        for (int it = 0; it < 16; ++it) {              // LDS -> global, coalesced
            int f = it * 192 + t;
            int row = f >> 4, c4 = f & 15;
            int gr = base + row;
            if (gr < cnt) {
                int dst = list ? list[gr] : gr;
                const float* s = &Xs[row * GSTRIDE + c4 * 4];
                float4 v = make_float4(s[0], s[1], s[2], s[3]);
                *(float4*)(xout + (size_t)dst * 64 + c4 * 4) = v;
            }
        }
    }
}

// ---------------- sparse residual: out[i] += x[j] @ W[k] per extra entry ----------------

__global__ __launch_bounds__(256) void residual(const float* __restrict__ xin,
                                                float* __restrict__ xout,
                                                const float* __restrict__ Wl,   // [27][64][64]
                                                const int2* __restrict__ extras,
                                                const int* __restrict__ cnt) {
    int m = *cnt; if (m > ECAP) m = ECAP;
    int nw = (int)((gridDim.x * blockDim.x) >> 6);
    int gw = (int)((blockIdx.x * blockDim.x + threadIdx.x) >> 6);
    int lane = threadIdx.x & 63;
    for (int e = gw; e < m; e += nw) {
        int eu = __builtin_amdgcn_readfirstlane(e);
        int2 pr = extras[eu];
        int i = __builtin_amdgcn_readfirstlane(pr.x >> 5);
        int k = __builtin_amdgcn_readfirstlane(pr.x & 31);
        int j = __builtin_amdgcn_readfirstlane(pr.y);
        const float* xj = xin + (size_t)j * 64;
        const float* Wk = Wl + k * 4096 + lane;
        float a0 = 0.f, a1 = 0.f;
#pragma unroll
        for (int c = 0; c < 64; c += 2) {
            a0 = fmaf(xj[c],     Wk[c * 64],       a0);
            a1 = fmaf(xj[c + 1], Wk[(c + 1) * 64], a1);
        }
        atomicAdd(&xout[(size_t)i * 64 + lane], a0 + a1);
    }
}

// ---------------- launch ----------------

extern "C" void kernel_launch(void* const* d_in, const int* in_sizes, int n_in,
                              void* d_out, int out_size, void* d_ws, size_t ws_size,
                              hipStream_t stream) {
    const float* features = (const float*)d_in[0];
    const float* Ws       = (const float*)d_in[1];   // [3][27][64][64]
    const int*   coors    = (const int*)d_in[2];
    int n = in_sizes[0] / 64;

    char* p = (char*)d_ws;
    unsigned long long* tab = (unsigned long long*)p; p += (size_t)HSIZE * 8;
    int* cnt  = (int*)p;
    int* scnt = cnt + 1;                              p += 256;
    int2* extras = (int2*)p;                          p += (size_t)ECAP * 8;
    int* flags = (int*)p;                             p += (((size_t)n * 4 + 255) & ~255ull);
    int* Slist = (int*)p;                             p += (((size_t)n * 4 + 255) & ~255ull);
    float* bufA = (float*)p;                          p += (((size_t)n * 256 + 255) & ~255ull);
    float* bufB = (float*)p;                          p += (((size_t)n * 256 + 255) & ~255ull);
    float* T  = (float*)p;                            p += 16384;
    float* P  = (float*)p;                            p += 16384;
    float* out = (float*)d_out;

    const float* W0  = Ws + 0 * 27 * 4096;
    const float* W1  = Ws + 1 * 27 * 4096;
    const float* W2  = Ws + 2 * 27 * 4096;
    const float* W0c = W0 + 13 * 4096;
    const float* W1c = W1 + 13 * 4096;
    const float* W2c = W2 + 13 * 4096;

    setup<<<(HSIZE + 255) / 256, 256, 0, stream>>>(tab, flags, n, cnt, scnt);
    hash_insert<<<(n + 255) / 256, 256, 0, stream>>>(coors, n, tab);
    mm64<<<16, 256, 0, stream>>>(W0c, W1c, T);       // T = W0c @ W1c
    mm64<<<16, 256, 0, stream>>>(T, W2c, P);         // P = T @ W2c
    build_extras<<<(n + 255) / 256, 256, 0, stream>>>(coors, n, tab, extras, cnt, flags);
    compact_S<<<(n + 255) / 256, 256, 0, stream>>>(flags, n, Slist, scnt);

    // dense collapsed 3-layer pass: out = features @ P
    int dtiles = (n + 191) / 192;
    gemm_tile<<<dtiles, 192, 0, stream>>>(features, out, P, nullptr, nullptr, n);

    // S-pass (closed set): per-layer propagation on S rows, then overwrite out rows
    gemm_tile<<<64, 192, 0, stream>>>(features, bufA, W0c, Slist, scnt, n);
    residual<<<64, 256, 0, stream>>>(features, bufA, W0, extras, cnt);
    gemm_tile<<<64, 192, 0, stream>>>(bufA, bufB, W1c, Slist, scnt, n);
    residual<<<64, 256, 0, stream>>>(bufA, bufB, W1, extras, cnt);
    gemm_tile<<<64, 192, 0, stream>>>(bufB, out, W2c, Slist, scnt, n);
    residual<<<64, 256, 0, stream>>>(bufB, out, W2, extras, cnt);
}

// Round 6
// 241.795 us; speedup vs baseline: 1.1270x; 1.1270x over previous
//
#include <hip/hip_runtime.h>

#define HBITS 19u
#define HSIZE (1u << HBITS)
#define HMASK (HSIZE - 1u)
#define ECAP  (1 << 20)           // extras capacity (entries)
#define EMPTY64 0xFFFFFFFFFFFFFFFFull

constexpr int CD = 41, CH = 1024, CW = 1024;

// ---------------- setup: clear hash table, flags, counters ----------------

__global__ __launch_bounds__(256) void setup(unsigned long long* __restrict__ tab,
                                             int* __restrict__ flags, int n,
                                             int* __restrict__ cnt, int* __restrict__ scnt) {
    unsigned i = blockIdx.x * blockDim.x + threadIdx.x;
    if (i < HSIZE) tab[i] = EMPTY64;
    if (i < (unsigned)n) flags[i] = 0;
    if (i == 0) { *cnt = 0; *scnt = 0; }
}

// ---------------- hash: 64-bit records (idx<<32 | lin), linear probe ----------------

__global__ __launch_bounds__(256) void hash_insert(const int* __restrict__ coors, int n,
                                                   unsigned long long* __restrict__ tab) {
    int i = blockIdx.x * blockDim.x + threadIdx.x;
    if (i >= n) return;
    int b = coors[4 * i], z = coors[4 * i + 1], y = coors[4 * i + 2], x = coors[4 * i + 3];
    unsigned lin = (((unsigned)b * CD + (unsigned)z) * CH + (unsigned)y) * CW + (unsigned)x;
    unsigned h = (lin * 2654435761u) >> (32u - HBITS);
    unsigned long long rec = ((unsigned long long)(unsigned)i << 32) | (unsigned long long)lin;
    while (true) {
        unsigned long long prev = atomicCAS(&tab[h], EMPTY64, rec);
        if (prev == EMPTY64) break;
        h = (h + 1u) & HMASK;
    }
}

__device__ __forceinline__ int hash_lookup(unsigned lin, const unsigned long long* __restrict__ tab) {
    unsigned h = (lin * 2654435761u) >> (32u - HBITS);
    while (true) {
        unsigned long long v = tab[h];
        if ((unsigned)v == lin) return (int)(v >> 32);
        if (v == EMPTY64) return -1;
        h = (h + 1u) & HMASK;
    }
}

// ---------------- build extras + Slist (dedupe via flags) + P (extra block) --------
// mirror symmetry: (i,k,j) valid <=> (j,26-k,i) valid -> scan k<13, emit both.
// The last grid block instead computes P = W0c@W1c@W2c (independent inputs).

__global__ __launch_bounds__(256) void build_and_prep(const int* __restrict__ coors, int n,
                                                      const unsigned long long* __restrict__ tab,
                                                      int2* __restrict__ extras,
                                                      int* __restrict__ cnt,
                                                      int* __restrict__ flags,
                                                      int* __restrict__ Slist,
                                                      int* __restrict__ scnt,
                                                      const float* __restrict__ Ws,
                                                      float* __restrict__ P,
                                                      int nblocks_extras) {
    __shared__ float T[4096];
    __shared__ float B[4096];
    int t = threadIdx.x;

    if ((int)blockIdx.x >= nblocks_extras) {
        // ---- weight-product block: P = (W0c @ W1c) @ W2c ----
        const float* W0 = Ws + (0 * 27 + 13) * 4096;
        const float* W1 = Ws + (1 * 27 + 13) * 4096;
        const float* W2 = Ws + (2 * 27 + 13) * 4096;
        for (int e = t; e < 4096; e += 256) B[e] = W1[e];
        __syncthreads();
        for (int e = t; e < 4096; e += 256) {
            int r = e >> 6, c = e & 63;
            float s = 0.f;
#pragma unroll 8
            for (int k2 = 0; k2 < 64; ++k2) s = fmaf(W0[r * 64 + k2], B[k2 * 64 + c], s);
            T[e] = s;
        }
        __syncthreads();
        for (int e = t; e < 4096; e += 256) B[e] = W2[e];
        __syncthreads();
        for (int e = t; e < 4096; e += 256) {
            int r = e >> 6, c = e & 63;
            float s = 0.f;
#pragma unroll 8
            for (int k2 = 0; k2 < 64; ++k2) s = fmaf(T[r * 64 + k2], B[k2 * 64 + c], s);
            P[e] = s;
        }
        return;
    }

    int i = blockIdx.x * 256 + t;
    if (i >= n) return;
    int b = coors[4 * i], z = coors[4 * i + 1], y = coors[4 * i + 2], x = coors[4 * i + 3];
    for (int k = 0; k < 13; ++k) {
        int dz = k / 9 - 1, dy = (k / 3) % 3 - 1, dx = k % 3 - 1;
        int nz = z + dz, ny = y + dy, nx = x + dx;
        if (nz < 0 || nz >= CD || ny < 0 || ny >= CH || nx < 0 || nx >= CW) continue;
        unsigned lin = (((unsigned)b * CD + (unsigned)nz) * CH + (unsigned)ny) * CW + (unsigned)nx;
        int j = hash_lookup(lin, tab);
        if (j >= 0) {
            int pos = atomicAdd(cnt, 2);
            if (pos + 1 < ECAP) {
                extras[pos]     = make_int2((i << 5) | k,        j);
                extras[pos + 1] = make_int2((j << 5) | (26 - k), i);
                if (atomicExch(&flags[i], 1) == 0) Slist[atomicAdd(scnt, 1)] = i;
                if (atomicExch(&flags[j], 1) == 0) Slist[atomicAdd(scnt, 1)] = j;
            }
        }
    }
}

// ---------------- tiled row GEMM: out[p] = x[p] @ Wm (row-major [cin][cout]) --------
// 192 points/block (3 waves). X staged in LDS (coalesced float4 in, stride-65 pad ->
// compute reads 2-way bank = free). lane = point; acc[64] static. W rows via uniform
// s_load. Output bounced through LDS for coalesced float4 stores.

#define GSTRIDE 65

__global__ __launch_bounds__(192, 2) void gemm_tile(const float* __restrict__ xin,
                                                    float* __restrict__ xout,
                                                    const float* __restrict__ Wm,
                                                    const int* __restrict__ list,     // null -> identity
                                                    const int* __restrict__ listCnt,  // null -> n
                                                    int n) {
    __shared__ float Xs[192 * GSTRIDE];   // 49,920 B
    int t = threadIdx.x;
    int lane = t & 63;
    int wv = t >> 6;
    int cnt = listCnt ? *listCnt : n;
    if (cnt <= 0) return;
    int ntiles = (cnt + 191) / 192;

    for (int tile = blockIdx.x; tile < ntiles; tile += gridDim.x) {
        if (tile != (int)blockIdx.x) __syncthreads();   // Xs reuse guard (loop only)
        int base = tile * 192;
#pragma unroll
        for (int it = 0; it < 16; ++it) {               // global -> LDS, coalesced
            int f = it * 192 + t;                       // float4 id 0..3071
            int row = f >> 4, c4 = f & 15;
            int gr = base + row;
            int src = gr < cnt ? gr : cnt - 1;
            if (list) src = list[src];
            float4 v = *(const float4*)(xin + (size_t)src * 64 + c4 * 4);
            float* d = &Xs[row * GSTRIDE + c4 * 4];
            d[0] = v.x; d[1] = v.y; d[2] = v.z; d[3] = v.w;
        }
        __syncthreads();

        int myrow = wv * 64 + lane;
        float* xr = &Xs[myrow * GSTRIDE];
        float acc[64];
#pragma unroll
        for (int o = 0; o < 64; ++o) acc[o] = 0.f;
#pragma unroll 2
        for (int c = 0; c < 64; ++c) {
            float xc = xr[c];
            const float* wr = Wm + c * 64;              // uniform -> s_load
#pragma unroll
            for (int o = 0; o < 64; ++o) acc[o] = fmaf(xc, wr[o], acc[o]);
        }
#pragma unroll
        for (int o = 0; o < 64; ++o) xr[o] = acc[o];    // own row only
        __syncthreads();
#pragma unroll
        for (int it = 0; it < 16; ++it) {               // LDS -> global, coalesced
            int f = it * 192 + t;
            int row = f >> 4, c4 = f & 15;
            int gr = base + row;
            if (gr < cnt) {
                int dst = list ? list[gr] : gr;
                const float* s = &Xs[row * GSTRIDE + c4 * 4];
                float4 v = make_float4(s[0], s[1], s[2], s[3]);
                *(float4*)(xout + (size_t)dst * 64 + c4 * 4) = v;
            }
        }
    }
}

// ---------------- sparse residual: out[i] += x[j] @ W[k] per extra entry ----------------

__global__ __launch_bounds__(256) void residual(const float* __restrict__ xin,
                                                float* __restrict__ xout,
                                                const float* __restrict__ Wl,   // [27][64][64]
                                                const int2* __restrict__ extras,
                                                const int* __restrict__ cnt) {
    int m = *cnt; if (m > ECAP) m = ECAP;
    int nw = (int)((gridDim.x * blockDim.x) >> 6);
    int gw = (int)((blockIdx.x * blockDim.x + threadIdx.x) >> 6);
    int lane = threadIdx.x & 63;
    for (int e = gw; e < m; e += nw) {
        int eu = __builtin_amdgcn_readfirstlane(e);
        int2 pr = extras[eu];
        int i = __builtin_amdgcn_readfirstlane(pr.x >> 5);
        int k = __builtin_amdgcn_readfirstlane(pr.x & 31);
        int j = __builtin_amdgcn_readfirstlane(pr.y);
        const float* xj = xin + (size_t)j * 64;
        const float* Wk = Wl + k * 4096 + lane;
        float a0 = 0.f, a1 = 0.f;
#pragma unroll
        for (int c = 0; c < 64; c += 2) {
            a0 = fmaf(xj[c],     Wk[c * 64],       a0);
            a1 = fmaf(xj[c + 1], Wk[(c + 1) * 64], a1);
        }
        atomicAdd(&xout[(size_t)i * 64 + lane], a0 + a1);
    }
}

// ---------------- launch ----------------

extern "C" void kernel_launch(void* const* d_in, const int* in_sizes, int n_in,
                              void* d_out, int out_size, void* d_ws, size_t ws_size,
                              hipStream_t stream) {
    const float* features = (const float*)d_in[0];
    const float* Ws       = (const float*)d_in[1];   // [3][27][64][64]
    const int*   coors    = (const int*)d_in[2];
    int n = in_sizes[0] / 64;

    char* p = (char*)d_ws;
    unsigned long long* tab = (unsigned long long*)p; p += (size_t)HSIZE * 8;
    int* cnt  = (int*)p;
    int* scnt = cnt + 1;                              p += 256;
    int2* extras = (int2*)p;                          p += (size_t)ECAP * 8;
    int* flags = (int*)p;                             p += (((size_t)n * 4 + 255) & ~255ull);
    int* Slist = (int*)p;                             p += (((size_t)n * 4 + 255) & ~255ull);
    float* bufA = (float*)p;                          p += (((size_t)n * 256 + 255) & ~255ull);
    float* bufB = (float*)p;                          p += (((size_t)n * 256 + 255) & ~255ull);
    float* P  = (float*)p;                            p += 16384;
    float* out = (float*)d_out;

    const float* W0  = Ws + 0 * 27 * 4096;
    const float* W1  = Ws + 1 * 27 * 4096;
    const float* W2  = Ws + 2 * 27 * 4096;
    const float* W0c = W0 + 13 * 4096;
    const float* W1c = W1 + 13 * 4096;
    const float* W2c = W2 + 13 * 4096;

    setup<<<(HSIZE + 255) / 256, 256, 0, stream>>>(tab, flags, n, cnt, scnt);
    hash_insert<<<(n + 255) / 256, 256, 0, stream>>>(coors, n, tab);
    int bext = (n + 255) / 256;
    build_and_prep<<<bext + 1, 256, 0, stream>>>(coors, n, tab, extras, cnt,
                                                 flags, Slist, scnt, Ws, P, bext);

    // dense collapsed 3-layer pass: out = features @ P  (1 tile per block)
    int dtiles = (n + 191) / 192;
    gemm_tile<<<dtiles, 192, 0, stream>>>(features, out, P, nullptr, nullptr, n);

    // S-pass (closed set): per-layer propagation on S rows, then overwrite out rows.
    // Wide grids: idle blocks exit instantly; active blocks do <=1 tile.
    gemm_tile<<<128, 192, 0, stream>>>(features, bufA, W0c, Slist, scnt, n);
    residual<<<256, 256, 0, stream>>>(features, bufA, W0, extras, cnt);
    gemm_tile<<<128, 192, 0, stream>>>(bufA, bufB, W1c, Slist, scnt, n);
    residual<<<256, 256, 0, stream>>>(bufA, bufB, W1, extras, cnt);
    gemm_tile<<<128, 192, 0, stream>>>(bufB, out, W2c, Slist, scnt, n);
    residual<<<256, 256, 0, stream>>>(bufB, out, W2, extras, cnt);
}